// Round 1
// baseline (774.287 us; speedup 1.0000x reference)
//
#include <hip/hip_runtime.h>
#include <cstdint>

#define NNUM 100
#define NCAT 100
#define CATC 100
#define NCOND 128
#define GN_EPS 1e-5f

typedef __attribute__((ext_vector_type(8))) short bfrag8;   // 8 bf16 = 4 VGPRs
typedef __attribute__((ext_vector_type(4))) float accf4;    // 4 fp32 acc

__device__ __forceinline__ float sigmoidf_(float x) { return 1.0f / (1.0f + __expf(-x)); }

__device__ __forceinline__ ushort f2bf(float f) {
    uint32_t u = __builtin_bit_cast(uint32_t, f);
    u += 0x7fffu + ((u >> 16) & 1u);   // round-to-nearest-even
    return (ushort)(u >> 16);
}
__device__ __forceinline__ float bf2f(ushort h) {
    return __builtin_bit_cast(float, (uint32_t)h << 16);
}

// ---------------------------------------------------------------------------
// One-time prep: W_cat fp32 [g][k][c] -> split-bf16 hi/lo planes laid out in
// MFMA B-fragment order, so the GEMM loads fragments directly with 16B
// global loads (L2-resident; 32 b-blocks share each g slice).
// Layout (ushort): Wf[g*32768 + ((t*4 + kk)*2 + plane)*512 + lane*8 + j]
//   where fragment (t,kk): c = t*16 + (lane&15), k = kk*32 + (lane>>4)*8 + j.
// Writes fully coalesced (16B/lane).
// ---------------------------------------------------------------------------
__global__ __launch_bounds__(256)
void prep_wcat(const float* __restrict__ W_cat, ushort* __restrict__ Wf)
{
    const int g    = blockIdx.x;
    const int lane = threadIdx.x & 63;
    const int w    = threadIdx.x >> 6;
    const float* Wg = W_cat + ((size_t)g << 14);
    ushort* Wfg = Wf + ((size_t)g << 15);
    #pragma unroll
    for (int i = 0; i < 8; ++i) {
        int p  = w * 8 + i;           // 0..31 (t,kk) pairs
        int t  = p >> 2, kk = p & 3;
        int c  = t * 16 + (lane & 15);
        int kb = kk * 32 + ((lane >> 4) << 3);
        ushort hi[8], lo[8];
        #pragma unroll
        for (int j = 0; j < 8; ++j) {
            float v = Wg[(kb + j) * NCOND + c];
            ushort h = f2bf(v);
            hi[j] = h;
            lo[j] = f2bf(v - bf2f(h));
        }
        int off = ((t * 4 + kk) * 2) * 512 + lane * 8;
        *(bfrag8*)(Wfg + off)       = *(const bfrag8*)hi;
        *(bfrag8*)(Wfg + off + 512) = *(const bfrag8*)lo;
    }
}

// ---------------------------------------------------------------------------
// Pass 1: per-column (g) GEMM with split-bf16 (hi/lo) 3-term MFMA.
//   z = A_hi@W_hi + A_hi@W_lo + A_lo@W_hi
// Single-pass: each row loaded once (float2/lane), stats via butterfly,
// normalized in-register, packed 4B hi/lo pairs into [m][k] LDS with XOR
// swizzle byte^=(m&7)<<4 (conflict-free writes, free 2-way frag reads).
// W fragments come straight from Wf (global, L2-hit). One barrier.
// LDS = 64 KB -> 2 blocks/CU.
// ---------------------------------------------------------------------------
template<int DIRECT>
__global__ __launch_bounds__(256, 2)
void cat_gemm_kernel(const int* __restrict__ x_cat,
                     const float* __restrict__ emb_table,
                     const float* __restrict__ gn_w,
                     const float* __restrict__ gn_b,
                     const ushort* __restrict__ Wf,
                     const float* __restrict__ b_cat,
                     float* __restrict__ dst)
{
    const int g    = blockIdx.y;
    const int b0   = blockIdx.x * 128;
    const int tid  = threadIdx.x;
    const int lane = tid & 63;
    const int w    = tid >> 6;    // wave 0..3

    __shared__ __align__(16) ushort Ahi[128 * 128];   // [m][k] swizzled, 32 KB
    __shared__ __align__(16) ushort Alo[128 * 128];   // 32 KB

    // this lane owns k = 2*lane, 2*lane+1 of every row it stages
    float2 gw = *(const float2*)(gn_w + g * NCOND + lane * 2);
    float2 gb = *(const float2*)(gn_b + g * NCOND + lane * 2);

    #pragma unroll 4
    for (int r = 0; r < 32; ++r) {
        int m = w * 32 + r;
        int b = b0 + m;
        int idx = x_cat[(size_t)b * NCAT + g];
        const float2* row = (const float2*)(emb_table + ((size_t)(g * CATC + idx) << 7));
        float2 v = row[lane];
        float s  = v.x + v.y;
        float ss = v.x * v.x + v.y * v.y;
        #pragma unroll
        for (int off = 32; off > 0; off >>= 1) {
            s  += __shfl_xor(s,  off, 64);
            ss += __shfl_xor(ss, off, 64);
        }
        float mean = s * 0.0078125f;
        float var  = fmaf(-mean, mean, ss * 0.0078125f);
        float rs   = rsqrtf(var + GN_EPS);
        float n0 = (v.x - mean) * rs * gw.x + gb.x;
        float n1 = (v.y - mean) * rs * gw.y + gb.y;
        ushort h0 = f2bf(n0), h1 = f2bf(n1);
        uint32_t hp = (uint32_t)h0 | ((uint32_t)h1 << 16);
        uint32_t lp = (uint32_t)f2bf(n0 - bf2f(h0)) | ((uint32_t)f2bf(n1 - bf2f(h1)) << 16);
        int bo = m * 256 + ((lane * 4) ^ ((m & 7) << 4));   // swizzled byte offset
        *(uint32_t*)((char*)Ahi + bo) = hp;
        *(uint32_t*)((char*)Alo + bo) = lp;
    }
    __syncthreads();

    accf4 acc[2][8];
    #pragma unroll
    for (int gi = 0; gi < 2; ++gi)
        #pragma unroll
        for (int t = 0; t < 8; ++t)
            acc[gi][t] = (accf4){0.f, 0.f, 0.f, 0.f};

    const ushort* Wfg = Wf + ((size_t)g << 15);
    const int row0 = w * 16 + (lane & 15);          // grp w
    const int sw   = (lane & 7) << 4;               // (row&7)<<4, same for row0/row0+64

    #pragma unroll
    for (int kk = 0; kk < 4; ++kk) {
        int colb = kk * 64 + ((lane >> 4) << 4);    // pre-swizzle byte col
        int o0 = row0 * 256 + (colb ^ sw);
        int o1 = o0 + 64 * 256;                      // row0+64
        bfrag8 ah0 = *(const bfrag8*)((const char*)Ahi + o0);
        bfrag8 al0 = *(const bfrag8*)((const char*)Alo + o0);
        bfrag8 ah1 = *(const bfrag8*)((const char*)Ahi + o1);
        bfrag8 al1 = *(const bfrag8*)((const char*)Alo + o1);
        const ushort* wbase = Wfg + kk * 1024 + lane * 8;
        #pragma unroll
        for (int t = 0; t < 8; ++t) {
            bfrag8 wh = *(const bfrag8*)(wbase + t * 4096);
            bfrag8 wl = *(const bfrag8*)(wbase + t * 4096 + 512);
            acc[0][t] = __builtin_amdgcn_mfma_f32_16x16x32_bf16(ah0, wh, acc[0][t], 0, 0, 0);
            acc[0][t] = __builtin_amdgcn_mfma_f32_16x16x32_bf16(ah0, wl, acc[0][t], 0, 0, 0);
            acc[0][t] = __builtin_amdgcn_mfma_f32_16x16x32_bf16(al0, wh, acc[0][t], 0, 0, 0);
            acc[1][t] = __builtin_amdgcn_mfma_f32_16x16x32_bf16(ah1, wh, acc[1][t], 0, 0, 0);
            acc[1][t] = __builtin_amdgcn_mfma_f32_16x16x32_bf16(ah1, wl, acc[1][t], 0, 0, 0);
            acc[1][t] = __builtin_amdgcn_mfma_f32_16x16x32_bf16(al1, wh, acc[1][t], 0, 0, 0);
        }
    }

    // ---- epilogue: + b_cat, sigmoid, store ----
    const float* bcg = b_cat + g * NCOND;
    const int colL = lane & 15;
    const int quad = lane >> 4;
    #pragma unroll
    for (int t = 0; t < 8; ++t) {
        int c = t * 16 + colL;
        float bc = bcg[c];
        #pragma unroll
        for (int gi = 0; gi < 2; ++gi) {
            int mbase = (w + gi * 4) * 16 + quad * 4;
            #pragma unroll
            for (int r = 0; r < 4; ++r) {
                int b = b0 + mbase + r;
                float v = sigmoidf_(acc[gi][t][r] + bc);
                if (DIRECT) {
                    dst[(size_t)b * (128 * 200) + (size_t)c * 200 + 100 + g] = v;
                } else {
                    dst[(size_t)b * (NCAT * NCOND) + g * NCOND + c] = v;
                }
            }
        }
    }
}

// ---------------------------------------------------------------------------
// Transpose W_num/b_num (100x128 -> 128x100) into ws for coalesced pass-2 reads
// ---------------------------------------------------------------------------
__global__ __launch_bounds__(256)
void transpose_wn(const float* __restrict__ W_num, const float* __restrict__ b_num,
                  float* __restrict__ Wt, float* __restrict__ Bt)
{
    int idx = blockIdx.x * 256 + threadIdx.x;
    if (idx < NCOND * NNUM) {
        int c = idx / NNUM, j = idx - c * NNUM;
        Wt[idx] = W_num[j * NCOND + c];
        Bt[idx] = b_num[j * NCOND + c];
    }
}

// ---------------------------------------------------------------------------
// Pass 2: per-sample. LDS-transpose the (100x128) cat tile, fuse num branch,
// write fully-coalesced 200-float rows of out[b, :, :].
// ---------------------------------------------------------------------------
__global__ __launch_bounds__(256)
void finalize_kernel(const float* __restrict__ ws_cat,
                     const float* __restrict__ Wt,   // [c][j]
                     const float* __restrict__ Bt,   // [c][j]
                     const float* __restrict__ x_num,
                     float* __restrict__ out)
{
    const int b   = blockIdx.x;
    const int tid = threadIdx.x;
    __shared__ float T[NCAT * 129];   // pad 129 -> conflict-free strided reads
    __shared__ float xr[NNUM];

    if (tid < NNUM) xr[tid] = x_num[b * NNUM + tid];

    const float4* src = (const float4*)(ws_cat + (size_t)b * (NCAT * NCOND));
    #pragma unroll 4
    for (int it = 0; it < 13; ++it) {
        int i4 = it * 256 + tid;
        if (i4 < (NCAT * NCOND) / 4) {
            float4 v = src[i4];
            int base = i4 * 4;
            int gg = base >> 7;
            int cc = base & 127;
            float* d = &T[gg * 129 + cc];
            d[0] = v.x; d[1] = v.y; d[2] = v.z; d[3] = v.w;
        }
    }
    __syncthreads();

    float* outb = out + (size_t)b * (NCOND * 200);
    #pragma unroll 4
    for (int it = 0; it < 100; ++it) {
        int o = it * 256 + tid;          // 0..25599
        int c = o / 200;
        int j = o - c * 200;
        float v;
        if (j < NNUM) {
            v = sigmoidf_(xr[j] * Wt[c * NNUM + j] + Bt[c * NNUM + j]);
        } else {
            v = T[(j - NNUM) * 129 + c];
        }
        outb[o] = v;
    }
}

// ---------------------------------------------------------------------------
// Fallback num-branch kernel (only used if ws too small for two-pass)
// ---------------------------------------------------------------------------
__global__ __launch_bounds__(256)
void num_direct(const float* __restrict__ x_num, const float* __restrict__ W_num,
                const float* __restrict__ b_num, float* __restrict__ out, int B)
{
    size_t i = (size_t)blockIdx.x * 256 + threadIdx.x;
    size_t total = (size_t)B * NCOND * NNUM;
    if (i >= total) return;
    int n = (int)(i % NNUM);
    size_t t = i / NNUM;
    int c = (int)(t % NCOND);
    int b = (int)(t / NCOND);
    float v = sigmoidf_(x_num[b * NNUM + n] * W_num[n * NCOND + c] + b_num[n * NCOND + c]);
    out[(size_t)b * (NCOND * 200) + (size_t)c * 200 + n] = v;
}

extern "C" void kernel_launch(void* const* d_in, const int* in_sizes, int n_in,
                              void* d_out, int out_size, void* d_ws, size_t ws_size,
                              hipStream_t stream)
{
    const float* x_num  = (const float*)d_in[0];
    const int*   x_cat  = (const int*)  d_in[1];
    const float* W_num  = (const float*)d_in[2];
    const float* b_num  = (const float*)d_in[3];
    const float* emb    = (const float*)d_in[4];
    const float* gn_w   = (const float*)d_in[5];
    const float* gn_b   = (const float*)d_in[6];
    const float* W_cat  = (const float*)d_in[7];
    const float* b_cat  = (const float*)d_in[8];
    float* out = (float*)d_out;

    const int B = in_sizes[0] / NNUM;                 // 4096
    const size_t cat_bytes = (size_t)B * NCAT * NCOND * sizeof(float);
    const size_t need = cat_bytes + 2 * (size_t)NCOND * NNUM * sizeof(float);

    dim3 gemm_grid(B / 128, NCAT);

    if (ws_size >= need) {
        float* ws_cat = (float*)d_ws;
        float* Wt = (float*)((char*)d_ws + cat_bytes);
        float* Bt = Wt + NCOND * NNUM;
        // Wf lives in the OUTPUT buffer as scratch (6.55 MB << 419 MB);
        // finalize_kernel overwrites every byte of out afterwards.
        ushort* Wf = (ushort*)out;
        prep_wcat<<<NCAT, 256, 0, stream>>>(W_cat, Wf);
        transpose_wn<<<(NCOND * NNUM + 255) / 256, 256, 0, stream>>>(W_num, b_num, Wt, Bt);
        cat_gemm_kernel<0><<<gemm_grid, 256, 0, stream>>>(x_cat, emb, gn_w, gn_b, Wf, b_cat, ws_cat);
        finalize_kernel<<<B, 256, 0, stream>>>(ws_cat, Wt, Bt, x_num, out);
    } else {
        // fallback: Wf in ws (6.55 MB), direct strided writes to out
        ushort* Wf = (ushort*)d_ws;
        prep_wcat<<<NCAT, 256, 0, stream>>>(W_cat, Wf);
        cat_gemm_kernel<1><<<gemm_grid, 256, 0, stream>>>(x_cat, emb, gn_w, gn_b, Wf, b_cat, out);
        size_t total = (size_t)B * NCOND * NNUM;
        num_direct<<<(total + 255) / 256, 256, 0, stream>>>(x_num, W_num, b_num, out, B);
    }
}

// Round 2
// 622.948 us; speedup vs baseline: 1.2429x; 1.2429x over previous
//
#include <hip/hip_runtime.h>
#include <cstdint>

#define NNUM 100
#define NCAT 100
#define CATC 100
#define NCOND 128
#define GN_EPS 1e-5f

typedef __attribute__((ext_vector_type(8))) short bfrag8;   // 8 bf16 = 4 VGPRs
typedef __attribute__((ext_vector_type(4))) float accf4;    // 4 fp32 acc

__device__ __forceinline__ float sigmoidf_(float x) { return 1.0f / (1.0f + __expf(-x)); }

__device__ __forceinline__ ushort f2bf(float f) {
    uint32_t u = __builtin_bit_cast(uint32_t, f);
    u += 0x7fffu + ((u >> 16) & 1u);   // round-to-nearest-even
    return (ushort)(u >> 16);
}
__device__ __forceinline__ float bf2f(ushort h) {
    return __builtin_bit_cast(float, (uint32_t)h << 16);
}

// ---------------------------------------------------------------------------
// One-time prep: W_cat fp32 [g][k][c] -> split-bf16 hi/lo planes laid out in
// MFMA B-fragment order, so the GEMM loads fragments directly with 16B
// global loads (L2-resident; 32 b-blocks share each g slice).
// Layout (ushort): Wf[g*32768 + ((t*4 + kk)*2 + plane)*512 + lane*8 + j]
//   where fragment (t,kk): c = t*16 + (lane&15), k = kk*32 + (lane>>4)*8 + j.
// ---------------------------------------------------------------------------
__global__ __launch_bounds__(256)
void prep_wcat(const float* __restrict__ W_cat, ushort* __restrict__ Wf)
{
    const int g    = blockIdx.x;
    const int lane = threadIdx.x & 63;
    const int w    = threadIdx.x >> 6;
    const float* Wg = W_cat + ((size_t)g << 14);
    ushort* Wfg = Wf + ((size_t)g << 15);
    #pragma unroll
    for (int i = 0; i < 8; ++i) {
        int p  = w * 8 + i;           // 0..31 (t,kk) pairs
        int t  = p >> 2, kk = p & 3;
        int c  = t * 16 + (lane & 15);
        int kb = kk * 32 + ((lane >> 4) << 3);
        ushort hi[8], lo[8];
        #pragma unroll
        for (int j = 0; j < 8; ++j) {
            float v = Wg[(kb + j) * NCOND + c];
            ushort h = f2bf(v);
            hi[j] = h;
            lo[j] = f2bf(v - bf2f(h));
        }
        int off = ((t * 4 + kk) * 2) * 512 + lane * 8;
        *(bfrag8*)(Wfg + off)       = *(const bfrag8*)hi;
        *(bfrag8*)(Wfg + off + 512) = *(const bfrag8*)lo;
    }
}

// ---------------------------------------------------------------------------
// Pass 1: per-column (g) GEMM, split-bf16 (hi/lo) 3-term MFMA.
//   z = A_hi@W_hi + A_hi@W_lo + A_lo@W_hi
// Stats/staging: float4 row loads, TWO rows in flight per wave (lanes 0-31 =
// row r, lanes 32-63 = row r+1), 5-stage butterfly within each 32-lane half,
// normalized in-register, packed into [m][k] LDS (XOR swizzle (m&7)<<4) via
// 8-byte ds_write_b64. One barrier. W fragments straight from Wf (L2-hit).
// LDS = 64 KB -> 2 blocks/CU.
// ---------------------------------------------------------------------------
template<int DIRECT>
__global__ __launch_bounds__(256, 2)
void cat_gemm_kernel(const int* __restrict__ x_cat,
                     const float* __restrict__ emb_table,
                     const float* __restrict__ gn_w,
                     const float* __restrict__ gn_b,
                     const ushort* __restrict__ Wf,
                     const float* __restrict__ b_cat,
                     float* __restrict__ dst)
{
    const int g    = blockIdx.y;
    const int b0   = blockIdx.x * 128;
    const int tid  = threadIdx.x;
    const int lane = tid & 63;
    const int w    = tid >> 6;    // wave 0..3

    __shared__ __align__(16) ushort Ahi[128 * 128];   // [m][k] swizzled, 32 KB
    __shared__ __align__(16) ushort Alo[128 * 128];   // 32 KB

    const int half = lane >> 5;       // which row of the pair
    const int l5   = lane & 31;       // owns k = 4*l5 .. 4*l5+3
    float4 gwv = *(const float4*)(gn_w + g * NCOND + l5 * 4);
    float4 gbv = *(const float4*)(gn_b + g * NCOND + l5 * 4);

    #pragma unroll 4
    for (int it = 0; it < 16; ++it) {
        int m = w * 32 + it * 2 + half;
        int b = b0 + m;
        int idx = x_cat[(size_t)b * NCAT + g];
        const float4* row = (const float4*)(emb_table + ((size_t)(g * CATC + idx) << 7));
        float4 v = row[l5];
        float s  = v.x + v.y + v.z + v.w;
        float ss = v.x * v.x + v.y * v.y + v.z * v.z + v.w * v.w;
        #pragma unroll
        for (int off = 16; off > 0; off >>= 1) {   // stays within 32-lane half
            s  += __shfl_xor(s,  off, 64);
            ss += __shfl_xor(ss, off, 64);
        }
        float mean = s * 0.0078125f;
        float var  = fmaf(-mean, mean, ss * 0.0078125f);
        float rs   = rsqrtf(var + GN_EPS);
        float n0 = fmaf((v.x - mean) * rs, gwv.x, gbv.x);
        float n1 = fmaf((v.y - mean) * rs, gwv.y, gbv.y);
        float n2 = fmaf((v.z - mean) * rs, gwv.z, gbv.z);
        float n3 = fmaf((v.w - mean) * rs, gwv.w, gbv.w);
        ushort h0 = f2bf(n0), h1 = f2bf(n1), h2 = f2bf(n2), h3 = f2bf(n3);
        uint2 hp = { (uint32_t)h0 | ((uint32_t)h1 << 16),
                     (uint32_t)h2 | ((uint32_t)h3 << 16) };
        uint2 lp = { (uint32_t)f2bf(n0 - bf2f(h0)) | ((uint32_t)f2bf(n1 - bf2f(h1)) << 16),
                     (uint32_t)f2bf(n2 - bf2f(h2)) | ((uint32_t)f2bf(n3 - bf2f(h3)) << 16) };
        int bo = m * 256 + ((l5 * 8) ^ ((m & 7) << 4));   // swizzled byte offset
        *(uint2*)((char*)Ahi + bo) = hp;
        *(uint2*)((char*)Alo + bo) = lp;
    }
    __syncthreads();

    accf4 acc[2][8];
    #pragma unroll
    for (int gi = 0; gi < 2; ++gi)
        #pragma unroll
        for (int t = 0; t < 8; ++t)
            acc[gi][t] = (accf4){0.f, 0.f, 0.f, 0.f};

    const ushort* Wfg = Wf + ((size_t)g << 15);
    const int row0 = w * 16 + (lane & 15);          // grp w
    const int sw   = (lane & 7) << 4;               // (row&7)<<4, same for row0/row0+64

    #pragma unroll
    for (int kk = 0; kk < 4; ++kk) {
        int colb = kk * 64 + ((lane >> 4) << 4);    // pre-swizzle byte col
        int o0 = row0 * 256 + (colb ^ sw);
        int o1 = o0 + 64 * 256;                      // row0+64
        bfrag8 ah0 = *(const bfrag8*)((const char*)Ahi + o0);
        bfrag8 al0 = *(const bfrag8*)((const char*)Alo + o0);
        bfrag8 ah1 = *(const bfrag8*)((const char*)Ahi + o1);
        bfrag8 al1 = *(const bfrag8*)((const char*)Alo + o1);
        const ushort* wbase = Wfg + kk * 1024 + lane * 8;
        #pragma unroll
        for (int t = 0; t < 8; ++t) {
            bfrag8 wh = *(const bfrag8*)(wbase + t * 4096);
            bfrag8 wl = *(const bfrag8*)(wbase + t * 4096 + 512);
            acc[0][t] = __builtin_amdgcn_mfma_f32_16x16x32_bf16(ah0, wh, acc[0][t], 0, 0, 0);
            acc[0][t] = __builtin_amdgcn_mfma_f32_16x16x32_bf16(ah0, wl, acc[0][t], 0, 0, 0);
            acc[0][t] = __builtin_amdgcn_mfma_f32_16x16x32_bf16(al0, wh, acc[0][t], 0, 0, 0);
            acc[1][t] = __builtin_amdgcn_mfma_f32_16x16x32_bf16(ah1, wh, acc[1][t], 0, 0, 0);
            acc[1][t] = __builtin_amdgcn_mfma_f32_16x16x32_bf16(ah1, wl, acc[1][t], 0, 0, 0);
            acc[1][t] = __builtin_amdgcn_mfma_f32_16x16x32_bf16(al1, wh, acc[1][t], 0, 0, 0);
        }
    }

    // ---- epilogue: + b_cat, sigmoid, store ----
    const float* bcg = b_cat + g * NCOND;
    const int colL = lane & 15;
    const int quad = lane >> 4;
    #pragma unroll
    for (int t = 0; t < 8; ++t) {
        int c = t * 16 + colL;
        float bc = bcg[c];
        #pragma unroll
        for (int gi = 0; gi < 2; ++gi) {
            int mbase = (w + gi * 4) * 16 + quad * 4;
            #pragma unroll
            for (int r = 0; r < 4; ++r) {
                int b = b0 + mbase + r;
                float v = sigmoidf_(acc[gi][t][r] + bc);
                if (DIRECT) {
                    dst[(size_t)b * (128 * 200) + (size_t)c * 200 + 100 + g] = v;
                } else {
                    dst[(size_t)b * (NCAT * NCOND) + g * NCOND + c] = v;
                }
            }
        }
    }
}

// ---------------------------------------------------------------------------
// Transpose W_num/b_num (100x128 -> 128x100) into ws for coalesced pass-2 reads
// ---------------------------------------------------------------------------
__global__ __launch_bounds__(256)
void transpose_wn(const float* __restrict__ W_num, const float* __restrict__ b_num,
                  float* __restrict__ Wt, float* __restrict__ Bt)
{
    int idx = blockIdx.x * 256 + threadIdx.x;
    if (idx < NCOND * NNUM) {
        int c = idx / NNUM, j = idx - c * NNUM;
        Wt[idx] = W_num[j * NCOND + c];
        Bt[idx] = b_num[j * NCOND + c];
    }
}

// ---------------------------------------------------------------------------
// Pass 2: per-sample. LDS-transpose the (100x128) cat tile, fuse num branch,
// write out[b,:,:] as 25 iterations of fully-coalesced float4 stores.
// The num/cat split (j=100) is float4-aligned: j4<25 num, j4>=25 cat.
// ---------------------------------------------------------------------------
__global__ __launch_bounds__(256)
void finalize_kernel(const float* __restrict__ ws_cat,
                     const float* __restrict__ Wt,   // [c][j]
                     const float* __restrict__ Bt,   // [c][j]
                     const float* __restrict__ x_num,
                     float* __restrict__ out)
{
    const int b   = blockIdx.x;
    const int tid = threadIdx.x;
    __shared__ float T[NCAT * 129];   // [g][c], pad 129 -> spread banks
    __shared__ float xr[NNUM];

    if (tid < NNUM) xr[tid] = x_num[b * NNUM + tid];

    const float4* src = (const float4*)(ws_cat + (size_t)b * (NCAT * NCOND));
    #pragma unroll
    for (int it = 0; it < 13; ++it) {
        int i4 = it * 256 + tid;
        if (i4 < (NCAT * NCOND) / 4) {
            float4 v = src[i4];
            int base = i4 * 4;
            int gg = base >> 7;
            int cc = base & 127;
            float* d = &T[gg * 129 + cc];
            d[0] = v.x; d[1] = v.y; d[2] = v.z; d[3] = v.w;
        }
    }
    __syncthreads();

    float4* outb = (float4*)(out + (size_t)b * (NCOND * 200));
    const float4* Wt4 = (const float4*)Wt;
    const float4* Bt4 = (const float4*)Bt;
    #pragma unroll
    for (int it = 0; it < 25; ++it) {
        int o4 = it * 256 + tid;          // 0..6399
        int c  = o4 / 50;
        int j4 = o4 - c * 50;
        float4 v;
        if (j4 < 25) {
            float4 wv = Wt4[c * 25 + j4];
            float4 bv = Bt4[c * 25 + j4];
            int j = j4 * 4;
            v.x = sigmoidf_(fmaf(xr[j],     wv.x, bv.x));
            v.y = sigmoidf_(fmaf(xr[j + 1], wv.y, bv.y));
            v.z = sigmoidf_(fmaf(xr[j + 2], wv.z, bv.z));
            v.w = sigmoidf_(fmaf(xr[j + 3], wv.w, bv.w));
        } else {
            int gg = (j4 - 25) * 4;
            v.x = T[(gg    ) * 129 + c];
            v.y = T[(gg + 1) * 129 + c];
            v.z = T[(gg + 2) * 129 + c];
            v.w = T[(gg + 3) * 129 + c];
        }
        outb[o4] = v;
    }
}

// ---------------------------------------------------------------------------
// Fallback num-branch kernel (only used if ws too small for two-pass)
// ---------------------------------------------------------------------------
__global__ __launch_bounds__(256)
void num_direct(const float* __restrict__ x_num, const float* __restrict__ W_num,
                const float* __restrict__ b_num, float* __restrict__ out, int B)
{
    size_t i = (size_t)blockIdx.x * 256 + threadIdx.x;
    size_t total = (size_t)B * NCOND * NNUM;
    if (i >= total) return;
    int n = (int)(i % NNUM);
    size_t t = i / NNUM;
    int c = (int)(t % NCOND);
    int b = (int)(t / NCOND);
    float v = sigmoidf_(x_num[b * NNUM + n] * W_num[n * NCOND + c] + b_num[n * NCOND + c]);
    out[(size_t)b * (NCOND * 200) + (size_t)c * 200 + n] = v;
}

extern "C" void kernel_launch(void* const* d_in, const int* in_sizes, int n_in,
                              void* d_out, int out_size, void* d_ws, size_t ws_size,
                              hipStream_t stream)
{
    const float* x_num  = (const float*)d_in[0];
    const int*   x_cat  = (const int*)  d_in[1];
    const float* W_num  = (const float*)d_in[2];
    const float* b_num  = (const float*)d_in[3];
    const float* emb    = (const float*)d_in[4];
    const float* gn_w   = (const float*)d_in[5];
    const float* gn_b   = (const float*)d_in[6];
    const float* W_cat  = (const float*)d_in[7];
    const float* b_cat  = (const float*)d_in[8];
    float* out = (float*)d_out;

    const int B = in_sizes[0] / NNUM;                 // 4096
    const size_t cat_bytes = (size_t)B * NCAT * NCOND * sizeof(float);
    const size_t need = cat_bytes + 2 * (size_t)NCOND * NNUM * sizeof(float);

    dim3 gemm_grid(B / 128, NCAT);

    if (ws_size >= need) {
        float* ws_cat = (float*)d_ws;
        float* Wt = (float*)((char*)d_ws + cat_bytes);
        float* Bt = Wt + NCOND * NNUM;
        // Wf lives in the OUTPUT buffer as scratch (6.55 MB << 419 MB);
        // finalize_kernel overwrites every byte of out afterwards.
        ushort* Wf = (ushort*)out;
        prep_wcat<<<NCAT, 256, 0, stream>>>(W_cat, Wf);
        transpose_wn<<<(NCOND * NNUM + 255) / 256, 256, 0, stream>>>(W_num, b_num, Wt, Bt);
        cat_gemm_kernel<0><<<gemm_grid, 256, 0, stream>>>(x_cat, emb, gn_w, gn_b, Wf, b_cat, ws_cat);
        finalize_kernel<<<B, 256, 0, stream>>>(ws_cat, Wt, Bt, x_num, out);
    } else {
        // fallback: Wf in ws (6.55 MB), direct strided writes to out
        ushort* Wf = (ushort*)d_ws;
        prep_wcat<<<NCAT, 256, 0, stream>>>(W_cat, Wf);
        cat_gemm_kernel<1><<<gemm_grid, 256, 0, stream>>>(x_cat, emb, gn_w, gn_b, Wf, b_cat, out);
        size_t total = (size_t)B * NCOND * NNUM;
        num_direct<<<(total + 255) / 256, 256, 0, stream>>>(x_num, W_num, b_num, out, B);
    }
}